// Round 1
// baseline (8259.818 us; speedup 1.0000x reference)
//
#include <hip/hip_runtime.h>

#define N_ 8
#define C_ 256
#define H_ 128
#define W_ 128
#define K_ 9
#define PAD_ 4
#define WPAD_ 12   // k padded to 12 floats so weight rows are float4-aligned

// ---------------- weight prep: w2[co][ci][12], k>=9 zeroed ----------------
__global__ __launch_bounds__(256) void prep_weights(const float* __restrict__ w,
                                                    float* __restrict__ w2) {
    int idx = blockIdx.x * 256 + threadIdx.x;
    if (idx >= C_ * C_ * WPAD_) return;
    int k = idx % WPAD_;
    int rest = idx / WPAD_;          // co*C + ci
    w2[idx] = (k < K_) ? w[rest * K_ + k] : 0.0f;
}

// ---------------- out row0 = fea row0 ----------------
__global__ __launch_bounds__(256) void copy_row0(const float* __restrict__ fea,
                                                 float* __restrict__ out) {
    int idx = blockIdx.x * 256 + threadIdx.x;
    if (idx >= N_ * C_ * W_) return;
    int w = idx % W_;
    int nc = idx / W_;
    size_t off = (size_t)nc * (H_ * W_) + w;   // h = 0
    out[off] = fea[off];
}

// ---------------- one scan step ----------------
// yout[n,co,h_out,w] = relu( sum_{ci,k} xprev[n,ci,h_prev,w+k-4]*W[co,ci,k] + bias[co] )
//                      + radd[n,co,h_out,w]
// grid: 256 blocks = 8 n * 4 w-chunks(32) * 8 co-chunks(32); 256 thr; 4 outputs/thread.
template<int WS>
__global__ __launch_bounds__(256) void step_kernel(
    const float* __restrict__ xprev, const float* __restrict__ radd,
    float* __restrict__ yout, const float* __restrict__ wsrc,
    const float* __restrict__ bias, int h_prev, int h_out)
{
    __shared__ float Xs[C_][40];           // 40 KB: 32 w + 8 halo per ci
    const int t  = threadIdx.x;
    const int bx = blockIdx.x;
    const int n  = bx & 7;
    const int wb = (bx >> 3) & 3;
    const int cb = bx >> 5;
    const int w0 = wb * 32;

    // ---- stage carry row slice (with zero halo) into LDS, coalesced ----
    {
        const size_t nbase = (size_t)n * C_ * (H_ * W_) + (size_t)h_prev * W_;
        for (int idx = t; idx < C_ * 40; idx += 256) {
            int ci = idx / 40;
            int j  = idx - ci * 40;
            int w  = w0 - PAD_ + j;
            float v = 0.0f;
            if ((unsigned)w < (unsigned)W_)
                v = xprev[nbase + (size_t)ci * (H_ * W_) + w];
            Xs[ci][j] = v;
        }
    }
    __syncthreads();

    const int co = cb * 32 + (t >> 3);
    const int w4 = (t & 7) * 4;            // local w offset, float4-aligned
    const float* wr = wsrc + (size_t)co * (C_ * WS);

    float acc0 = 0.f, acc1 = 0.f, acc2 = 0.f, acc3 = 0.f;

    auto ldw = [&](int ci, float wk[12]) {
        if (WS == WPAD_) {
            float4 a = *(const float4*)&wr[ci * WPAD_];
            float4 b = *(const float4*)&wr[ci * WPAD_ + 4];
            float4 c = *(const float4*)&wr[ci * WPAD_ + 8];
            wk[0]=a.x; wk[1]=a.y; wk[2]=a.z; wk[3]=a.w;
            wk[4]=b.x; wk[5]=b.y; wk[6]=b.z; wk[7]=b.w;
            wk[8]=c.x; wk[9]=0.f; wk[10]=0.f; wk[11]=0.f;
        } else {
            #pragma unroll
            for (int k = 0; k < K_; k++) wk[k] = wr[ci * K_ + k];
            wk[9]=0.f; wk[10]=0.f; wk[11]=0.f;
        }
    };
    auto ldx = [&](int ci, float xv[12]) {
        float4 a = *(const float4*)&Xs[ci][w4];
        float4 b = *(const float4*)&Xs[ci][w4 + 4];
        float4 c = *(const float4*)&Xs[ci][w4 + 8];
        xv[0]=a.x; xv[1]=a.y; xv[2]=a.z; xv[3]=a.w;
        xv[4]=b.x; xv[5]=b.y; xv[6]=b.z; xv[7]=b.w;
        xv[8]=c.x; xv[9]=c.y; xv[10]=c.z; xv[11]=c.w;
    };
    auto comp = [&](const float wk[12], const float xv[12]) {
        #pragma unroll
        for (int k = 0; k < K_; k++) {
            acc0 = fmaf(wk[k], xv[k],     acc0);
            acc1 = fmaf(wk[k], xv[k + 1], acc1);
            acc2 = fmaf(wk[k], xv[k + 2], acc2);
            acc3 = fmaf(wk[k], xv[k + 3], acc3);
        }
    };

    // 1-deep software pipeline, 2 ci per stage (only 1 wave/SIMD -> need ILP)
    float wA[12], xA[12], wB[12], xB[12], wC[12], xC[12], wD[12], xD[12];
    ldw(0, wA); ldx(0, xA);
    ldw(1, wB); ldx(1, xB);
    #pragma unroll 2
    for (int i = 0; i < (C_ / 2) - 1; i++) {
        int nc = 2 * i + 2;
        ldw(nc, wC);     ldx(nc, xC);
        ldw(nc + 1, wD); ldx(nc + 1, xD);
        comp(wA, xA);
        comp(wB, xB);
        #pragma unroll
        for (int q = 0; q < 12; q++) {
            wA[q] = wC[q]; xA[q] = xC[q];
            wB[q] = wD[q]; xB[q] = xD[q];
        }
    }
    comp(wA, xA);
    comp(wB, xB);

    const float b = bias[co];
    const size_t obase = (((size_t)n * C_ + co) * H_ + h_out) * W_ + w0 + w4;
    float4 r = *(const float4*)&radd[obase];
    float4 o;
    o.x = fmaxf(acc0 + b, 0.f) + r.x;
    o.y = fmaxf(acc1 + b, 0.f) + r.y;
    o.z = fmaxf(acc2 + b, 0.f) + r.z;
    o.w = fmaxf(acc3 + b, 0.f) + r.w;
    *(float4*)&yout[obase] = o;
}

extern "C" void kernel_launch(void* const* d_in, const int* in_sizes, int n_in,
                              void* d_out, int out_size, void* d_ws, size_t ws_size,
                              hipStream_t stream) {
    const float* fea    = (const float*)d_in[0];
    const float* weight = (const float*)d_in[1];
    const float* bias   = (const float*)d_in[2];
    float* out = (float*)d_out;

    const size_t w2_bytes = (size_t)C_ * C_ * WPAD_ * sizeof(float);
    const bool padded = (ws_size >= w2_bytes) && (d_ws != nullptr);
    float* w2 = (float*)d_ws;

    if (padded)
        prep_weights<<<(C_ * C_ * WPAD_ + 255) / 256, 256, 0, stream>>>(weight, w2);

    copy_row0<<<(N_ * C_ * W_ + 255) / 256, 256, 0, stream>>>(fea, out);

    if (padded) {
        for (int h = 1; h < H_; h++)
            step_kernel<WPAD_><<<256, 256, 0, stream>>>(out, fea, out, w2, bias, h - 1, h);
        for (int h = H_ - 2; h >= 1; h--)
            step_kernel<WPAD_><<<256, 256, 0, stream>>>(out, out, out, w2, bias, h + 1, h);
    } else {
        for (int h = 1; h < H_; h++)
            step_kernel<K_><<<256, 256, 0, stream>>>(out, fea, out, weight, bias, h - 1, h);
        for (int h = H_ - 2; h >= 1; h--)
            step_kernel<K_><<<256, 256, 0, stream>>>(out, out, out, weight, bias, h + 1, h);
    }
}

// Round 2
// 6333.356 us; speedup vs baseline: 1.3042x; 1.3042x over previous
//
#include <hip/hip_runtime.h>

typedef _Float16 f16;
typedef _Float16 f16x8 __attribute__((ext_vector_type(8)));
typedef _Float16 f16x4 __attribute__((ext_vector_type(4)));
typedef float    f32x4 __attribute__((ext_vector_type(4)));

#define N_   8
#define C_   256
#define H_   128
#define W_   128
#define K_   9
#define PAD_ 4
#define WP_  136            // padded w index: wp = w + 4, rows 0..135, pads zeroed

#define WELEMS (16*9*8*64*8)        // 589824 = C_*C_*K_ in fragment-linear layout
#define XT_SZ  (N_*WP_*C_)          // 278528 elements per (buf, hi/lo)

// ---------------- weight prep: fragment-linear fp16 hi/lo ----------------
// layout: t = ((((ct*9 + k)*8 + cic)*64 + lane)*8 + j
// co = ct*16 + (lane&15); ci = cic*32 + (lane>>4)*8 + j
__global__ __launch_bounds__(256) void prep_w(const float* __restrict__ w,
                                              f16* __restrict__ wh, f16* __restrict__ wl) {
    int t = blockIdx.x * 256 + threadIdx.x;
    if (t >= WELEMS) return;
    int j = t & 7;      int idx = t >> 3;
    int lane = idx & 63; idx >>= 6;
    int cic = idx & 7;   idx >>= 3;
    int k = idx % 9;     int ct = idx / 9;
    int co = ct * 16 + (lane & 15);
    int ci = cic * 32 + (lane >> 4) * 8 + j;
    float wf = w[(co * C_ + ci) * K_ + k];
    f16 hi = (f16)wf;
    f16 lo = (f16)(wf - (float)hi);
    wh[t] = hi;  wl[t] = lo;
}

// ---------------- Xt init: buf0 = fea row0 (transposed hi/lo), zero pads of both bufs ----------------
__global__ __launch_bounds__(256) void prep_x0(const float* __restrict__ fea,
                                               f16* __restrict__ x0h, f16* __restrict__ x0l,
                                               f16* __restrict__ x1h, f16* __restrict__ x1l) {
    int t = blockIdx.x * 256 + threadIdx.x;
    if (t >= XT_SZ) return;
    int ci = t & 255;
    int wp = (t >> 8) % WP_;
    int n  = t / (WP_ * 256);
    int w  = wp - PAD_;
    bool pad = (unsigned)w >= (unsigned)W_;
    float v = pad ? 0.0f : fea[((size_t)(n * C_ + ci) * H_ + 0) * W_ + w];
    f16 hi = (f16)v;
    f16 lo = (f16)(v - (float)hi);
    x0h[t] = hi;  x0l[t] = lo;
    if (pad) { x1h[t] = (f16)0.f; x1l[t] = (f16)0.f; }   // steps never write pad rows
}

// ---------------- out row0 = fea row0 ----------------
__global__ __launch_bounds__(256) void copy_row0(const float* __restrict__ fea,
                                                 float* __restrict__ out) {
    int idx = blockIdx.x * 256 + threadIdx.x;
    if (idx >= N_ * C_ * W_) return;
    int w = idx % W_;
    int nc = idx / W_;
    size_t off = (size_t)nc * (H_ * W_) + w;   // h = 0
    out[off] = fea[off];
}

// ---------------- one scan step (MFMA, fp16 split 3-product) ----------------
// reads carry row from (xh,xl) [n][wp][ci]; writes new row to out (fp32) and (yh,yl).
// radd = radd_base[n, co, h_out, w].
__global__ __launch_bounds__(256) void step_mfma(
    const f16* __restrict__ xh, const f16* __restrict__ xl,
    f16* __restrict__ yh, f16* __restrict__ yl,
    const f16* __restrict__ wh, const f16* __restrict__ wl,
    const float* __restrict__ bias, const float* __restrict__ radd_base,
    float* __restrict__ out, int h_out)
{
    // XCD-aware swizzle (256 % 8 == 0, bijective): XCD x owns ct {2x, 2x+1}
    int p = blockIdx.x;
    int L = (p & 7) * 32 + (p >> 3);
    int ct = L >> 4;            // co tile 0..15 (16 co each)
    int r_ = L & 15;
    int n  = r_ >> 1;
    int w0 = (r_ & 1) * 64;     // block covers w0 .. w0+63

    int wi = threadIdx.x >> 6;  // wave id 0..3 -> nw sub-tile
    int l  = threadIdx.x & 63;

    const int wcol  = w0 + wi * 16 + (l & 15);   // this lane's output w
    const int cio   = (l >> 4) * 8;              // ci sub-offset within chunk

    f32x4 aP0{}, aP1{}, aP2{}, aQ0{}, aQ1{}, aQ2{};

    for (int k = 0; k < K_; k++) {
        // wp = (w + 4) + (k - 4) = w + k  -> pad rows absorb the halo
        const size_t xrow = ((size_t)n * WP_ + (wcol + k)) * C_ + cio;
        const size_t arow = (((size_t)ct * 9 + k) * 8) * 512 + (size_t)l * 8;
        #pragma unroll
        for (int cic = 0; cic < 8; cic++) {
            f16x8 ah = *(const f16x8*)&wh[arow + (size_t)cic * 512];
            f16x8 al = *(const f16x8*)&wl[arow + (size_t)cic * 512];
            f16x8 bh = *(const f16x8*)&xh[xrow + cic * 32];
            f16x8 bl = *(const f16x8*)&xl[xrow + cic * 32];
            if (cic & 1) {
                aQ0 = __builtin_amdgcn_mfma_f32_16x16x32_f16(ah, bh, aQ0, 0, 0, 0);
                aQ1 = __builtin_amdgcn_mfma_f32_16x16x32_f16(ah, bl, aQ1, 0, 0, 0);
                aQ2 = __builtin_amdgcn_mfma_f32_16x16x32_f16(al, bh, aQ2, 0, 0, 0);
            } else {
                aP0 = __builtin_amdgcn_mfma_f32_16x16x32_f16(ah, bh, aP0, 0, 0, 0);
                aP1 = __builtin_amdgcn_mfma_f32_16x16x32_f16(ah, bl, aP1, 0, 0, 0);
                aP2 = __builtin_amdgcn_mfma_f32_16x16x32_f16(al, bh, aP2, 0, 0, 0);
            }
        }
    }
    f32x4 s = aP0 + aP1 + aP2 + aQ0 + aQ1 + aQ2;

    // epilogue: C/D layout col = lane&15 (w), row = (lane>>4)*4 + r (co)
    const int co0 = ct * 16 + (l >> 4) * 4;
    float4 bv = *(const float4*)&bias[co0];
    const float bvr[4] = {bv.x, bv.y, bv.z, bv.w};
    const size_t obase = ((size_t)(n * C_ + co0) * H_ + h_out) * W_ + wcol;

    float y[4];
    #pragma unroll
    for (int r = 0; r < 4; r++) {
        float v = fmaxf(s[r] + bvr[r], 0.0f);
        v += radd_base[obase + (size_t)r * (H_ * W_)];
        out[obase + (size_t)r * (H_ * W_)] = v;
        y[r] = v;
    }
    // transposed fp16 hi/lo for the next step's B operand
    const size_t xoff = ((size_t)n * WP_ + (wcol + PAD_)) * C_ + co0;
    f16x4 hv, lv;
    #pragma unroll
    for (int r = 0; r < 4; r++) {
        f16 hi = (f16)y[r];
        hv[r] = hi;
        lv[r] = (f16)(y[r] - (float)hi);
    }
    *(f16x4*)&yh[xoff] = hv;
    *(f16x4*)&yl[xoff] = lv;
}

// ---------------- fallback (ws too small): round-1 fp32 step, raw weights ----------------
__global__ __launch_bounds__(256) void step_f32(
    const float* __restrict__ xprev, const float* __restrict__ radd,
    float* __restrict__ yout, const float* __restrict__ wsrc,
    const float* __restrict__ bias, int h_prev, int h_out)
{
    __shared__ float Xs[C_][40];
    const int t  = threadIdx.x;
    const int bx = blockIdx.x;
    const int n  = bx & 7;
    const int wb = (bx >> 3) & 3;
    const int cb = bx >> 5;
    const int w0 = wb * 32;
    {
        const size_t nbase = (size_t)n * C_ * (H_ * W_) + (size_t)h_prev * W_;
        for (int idx = t; idx < C_ * 40; idx += 256) {
            int ci = idx / 40;
            int j  = idx - ci * 40;
            int w  = w0 - PAD_ + j;
            float v = 0.0f;
            if ((unsigned)w < (unsigned)W_)
                v = xprev[nbase + (size_t)ci * (H_ * W_) + w];
            Xs[ci][j] = v;
        }
    }
    __syncthreads();
    const int co = cb * 32 + (t >> 3);
    const int w4 = (t & 7) * 4;
    const float* wr = wsrc + (size_t)co * (C_ * K_);
    float acc0 = 0.f, acc1 = 0.f, acc2 = 0.f, acc3 = 0.f;
    for (int ci = 0; ci < C_; ci++) {
        float wk[K_];
        #pragma unroll
        for (int k = 0; k < K_; k++) wk[k] = wr[ci * K_ + k];
        float xv[12];
        float4 a = *(const float4*)&Xs[ci][w4];
        float4 b = *(const float4*)&Xs[ci][w4 + 4];
        float4 c = *(const float4*)&Xs[ci][w4 + 8];
        xv[0]=a.x; xv[1]=a.y; xv[2]=a.z; xv[3]=a.w;
        xv[4]=b.x; xv[5]=b.y; xv[6]=b.z; xv[7]=b.w;
        xv[8]=c.x; xv[9]=c.y; xv[10]=c.z; xv[11]=c.w;
        #pragma unroll
        for (int k = 0; k < K_; k++) {
            acc0 = fmaf(wk[k], xv[k],     acc0);
            acc1 = fmaf(wk[k], xv[k + 1], acc1);
            acc2 = fmaf(wk[k], xv[k + 2], acc2);
            acc3 = fmaf(wk[k], xv[k + 3], acc3);
        }
    }
    const float b = bias[co];
    const size_t obase = (((size_t)n * C_ + co) * H_ + h_out) * W_ + w0 + w4;
    float4 r = *(const float4*)&radd[obase];
    float4 o;
    o.x = fmaxf(acc0 + b, 0.f) + r.x;
    o.y = fmaxf(acc1 + b, 0.f) + r.y;
    o.z = fmaxf(acc2 + b, 0.f) + r.z;
    o.w = fmaxf(acc3 + b, 0.f) + r.w;
    *(float4*)&yout[obase] = o;
}

extern "C" void kernel_launch(void* const* d_in, const int* in_sizes, int n_in,
                              void* d_out, int out_size, void* d_ws, size_t ws_size,
                              hipStream_t stream) {
    const float* fea    = (const float*)d_in[0];
    const float* weight = (const float*)d_in[1];
    const float* bias   = (const float*)d_in[2];
    float* out = (float*)d_out;

    // ws layout: Wh | Wl | Xt[buf0]h | Xt[buf0]l | Xt[buf1]h | Xt[buf1]l
    const size_t need = (size_t)2 * WELEMS * 2 + (size_t)4 * XT_SZ * 2;

    copy_row0<<<(N_ * C_ * W_ + 255) / 256, 256, 0, stream>>>(fea, out);

    if (ws_size >= need && d_ws != nullptr) {
        f16* wh  = (f16*)d_ws;
        f16* wl  = wh + WELEMS;
        f16* x0h = wl + WELEMS;
        f16* x0l = x0h + XT_SZ;
        f16* x1h = x0l + XT_SZ;
        f16* x1l = x1h + XT_SZ;
        f16* bh[2] = {x0h, x1h};
        f16* bl[2] = {x0l, x1l};

        prep_w<<<(WELEMS + 255) / 256, 256, 0, stream>>>(weight, wh, wl);
        prep_x0<<<(XT_SZ + 255) / 256, 256, 0, stream>>>(fea, x0h, x0l, x1h, x1l);

        int cur = 0;
        for (int h = 1; h < H_; h++) {        // forward: radd = fea row h
            step_mfma<<<256, 256, 0, stream>>>(bh[cur], bl[cur], bh[1 - cur], bl[1 - cur],
                                               wh, wl, bias, fea, out, h);
            cur ^= 1;
        }
        for (int h = H_ - 2; h >= 1; h--) {   // backward: radd = forward full row h (still in out)
            step_mfma<<<256, 256, 0, stream>>>(bh[cur], bl[cur], bh[1 - cur], bl[1 - cur],
                                               wh, wl, bias, out, out, h);
            cur ^= 1;
        }
    } else {
        for (int h = 1; h < H_; h++)
            step_f32<<<256, 256, 0, stream>>>(out, fea, out, weight, bias, h - 1, h);
        for (int h = H_ - 2; h >= 1; h--)
            step_f32<<<256, 256, 0, stream>>>(out, out, out, weight, bias, h + 1, h);
    }
}

// Round 3
// 5883.870 us; speedup vs baseline: 1.4038x; 1.0764x over previous
//
#include <hip/hip_runtime.h>

typedef _Float16 f16;
typedef _Float16 f16x8 __attribute__((ext_vector_type(8)));
typedef _Float16 f16x4 __attribute__((ext_vector_type(4)));
typedef float    f32x4 __attribute__((ext_vector_type(4)));

#define N_   8
#define C_   256
#define H_   128
#define W_   128
#define K_   9
#define PAD_ 4
#define WP_  136            // padded w index: wp = w + 4, rows 0..135, pads zeroed

#define WELEMS (16*9*8*64*8)        // 589824 = C_*C_*K_ in fragment-linear layout
#define XT_SZ  (N_*WP_*C_)          // 278528 elements per (buf, hi/lo)

// ---------------- weight prep: fragment-linear fp16 hi/lo ----------------
// layout: t = ((((ct*9 + k)*8 + cic)*64 + lane)*8 + j
// co = ct*16 + (lane&15); ci = cic*32 + (lane>>4)*8 + j
__global__ __launch_bounds__(256) void prep_w(const float* __restrict__ w,
                                              f16* __restrict__ wh, f16* __restrict__ wl) {
    int t = blockIdx.x * 256 + threadIdx.x;
    if (t >= WELEMS) return;
    int j = t & 7;      int idx = t >> 3;
    int lane = idx & 63; idx >>= 6;
    int cic = idx & 7;   idx >>= 3;
    int k = idx % 9;     int ct = idx / 9;
    int co = ct * 16 + (lane & 15);
    int ci = cic * 32 + (lane >> 4) * 8 + j;
    float wf = w[(co * C_ + ci) * K_ + k];
    f16 hi = (f16)wf;
    f16 lo = (f16)(wf - (float)hi);
    wh[t] = hi;  wl[t] = lo;
}

// ---------------- Xt init: buf0 = fea row0 (transposed hi/lo), zero pads of both bufs ----------------
__global__ __launch_bounds__(256) void prep_x0(const float* __restrict__ fea,
                                               f16* __restrict__ x0h, f16* __restrict__ x0l,
                                               f16* __restrict__ x1h, f16* __restrict__ x1l) {
    int t = blockIdx.x * 256 + threadIdx.x;
    if (t >= XT_SZ) return;
    int ci = t & 255;
    int wp = (t >> 8) % WP_;
    int n  = t / (WP_ * 256);
    int w  = wp - PAD_;
    bool pad = (unsigned)w >= (unsigned)W_;
    float v = pad ? 0.0f : fea[((size_t)(n * C_ + ci) * H_ + 0) * W_ + w];
    f16 hi = (f16)v;
    f16 lo = (f16)(v - (float)hi);
    x0h[t] = hi;  x0l[t] = lo;
    if (pad) { x1h[t] = (f16)0.f; x1l[t] = (f16)0.f; }   // steps never write pad rows
}

// ---------------- out row0 = fea row0 ----------------
__global__ __launch_bounds__(256) void copy_row0(const float* __restrict__ fea,
                                                 float* __restrict__ out) {
    int idx = blockIdx.x * 256 + threadIdx.x;
    if (idx >= N_ * C_ * W_) return;
    int w = idx % W_;
    int nc = idx / W_;
    size_t off = (size_t)nc * (H_ * W_) + w;   // h = 0
    out[off] = fea[off];
}

// ---------------- one scan step (MFMA, fp16 split 3-product, 16-wave K-split) ----------------
// reads carry row from (xh,xl) [n][wp][ci]; writes new row to out (fp32) and (yh,yl).
// 256 blocks x 1024 threads. wave wi: w-subtile (wi&3), K-partition kp=wi>>2 (cic 2kp,2kp+1).
__global__ __launch_bounds__(1024) void step_mfma(
    const f16* __restrict__ xh, const f16* __restrict__ xl,
    f16* __restrict__ yh, f16* __restrict__ yl,
    const f16* __restrict__ wh, const f16* __restrict__ wl,
    const float* __restrict__ bias, const float* __restrict__ radd_base,
    float* __restrict__ out, int h_out)
{
    __shared__ f32x4 red[16][64];           // 16 KB cross-wave K-reduction

    // XCD-aware swizzle (256 % 8 == 0, bijective): XCD x owns ct {2x, 2x+1}
    int p = blockIdx.x;
    int L = (p & 7) * 32 + (p >> 3);
    int ct = L >> 4;            // co tile 0..15 (16 co each)
    int r_ = L & 15;
    int n  = r_ >> 1;
    int w0 = (r_ & 1) * 64;     // block covers w0 .. w0+63

    const int wi = threadIdx.x >> 6;        // wave id 0..15
    const int l  = threadIdx.x & 63;
    const int ws = wi & 3;                  // w sub-tile
    const int kp = wi >> 2;                 // K partition
    const int c0 = 2 * kp;                  // this wave's cic chunks: c0, c0+1

    const int wcol = w0 + ws * 16 + (l & 15);   // this lane's output w
    const int cio  = (l >> 4) * 8;              // ci sub-offset within chunk

    f32x4 aP0{}, aP1{}, aP2{}, aQ0{}, aQ1{}, aQ2{};

    #pragma unroll
    for (int k = 0; k < K_; k++) {
        // wp = (w + 4) + (k - 4) = w + k  -> pad rows absorb the halo
        const size_t xrow = ((size_t)n * WP_ + (wcol + k)) * C_ + cio;
        const size_t arow = (((size_t)ct * 9 + k) * 8 + c0) * 512 + (size_t)l * 8;
        f16x8 ah0 = *(const f16x8*)&wh[arow];
        f16x8 al0 = *(const f16x8*)&wl[arow];
        f16x8 bh0 = *(const f16x8*)&xh[xrow + c0 * 32];
        f16x8 bl0 = *(const f16x8*)&xl[xrow + c0 * 32];
        f16x8 ah1 = *(const f16x8*)&wh[arow + 512];
        f16x8 al1 = *(const f16x8*)&wl[arow + 512];
        f16x8 bh1 = *(const f16x8*)&xh[xrow + c0 * 32 + 32];
        f16x8 bl1 = *(const f16x8*)&xl[xrow + c0 * 32 + 32];
        aP0 = __builtin_amdgcn_mfma_f32_16x16x32_f16(ah0, bh0, aP0, 0, 0, 0);
        aP1 = __builtin_amdgcn_mfma_f32_16x16x32_f16(ah0, bl0, aP1, 0, 0, 0);
        aP2 = __builtin_amdgcn_mfma_f32_16x16x32_f16(al0, bh0, aP2, 0, 0, 0);
        aQ0 = __builtin_amdgcn_mfma_f32_16x16x32_f16(ah1, bh1, aQ0, 0, 0, 0);
        aQ1 = __builtin_amdgcn_mfma_f32_16x16x32_f16(ah1, bl1, aQ1, 0, 0, 0);
        aQ2 = __builtin_amdgcn_mfma_f32_16x16x32_f16(al1, bh1, aQ2, 0, 0, 0);
    }
    f32x4 s = (aP0 + aP1 + aP2) + (aQ0 + aQ1 + aQ2);

    red[wi][l] = s;
    __syncthreads();
    if (wi >= 4) return;

    s = (red[wi][l] + red[wi + 4][l]) + (red[wi + 8][l] + red[wi + 12][l]);

    // epilogue: C/D layout col = lane&15 (w), row = (lane>>4)*4 + r (co)
    const int co0 = ct * 16 + (l >> 4) * 4;
    float4 bv = *(const float4*)&bias[co0];
    const float bvr[4] = {bv.x, bv.y, bv.z, bv.w};
    const size_t obase = ((size_t)(n * C_ + co0) * H_ + h_out) * W_ + wcol;

    float y[4];
    #pragma unroll
    for (int r = 0; r < 4; r++) {
        float v = fmaxf(s[r] + bvr[r], 0.0f);
        v += radd_base[obase + (size_t)r * (H_ * W_)];
        out[obase + (size_t)r * (H_ * W_)] = v;
        y[r] = v;
    }
    // transposed fp16 hi/lo for the next step's B operand
    const size_t xoff = ((size_t)n * WP_ + (wcol + PAD_)) * C_ + co0;
    f16x4 hv, lv;
    #pragma unroll
    for (int r = 0; r < 4; r++) {
        f16 hi = (f16)y[r];
        hv[r] = hi;
        lv[r] = (f16)(y[r] - (float)hi);
    }
    *(f16x4*)&yh[xoff] = hv;
    *(f16x4*)&yl[xoff] = lv;
}

// ---------------- fallback (ws too small): fp32 step, raw weights ----------------
__global__ __launch_bounds__(256) void step_f32(
    const float* __restrict__ xprev, const float* __restrict__ radd,
    float* __restrict__ yout, const float* __restrict__ wsrc,
    const float* __restrict__ bias, int h_prev, int h_out)
{
    __shared__ float Xs[C_][40];
    const int t  = threadIdx.x;
    const int bx = blockIdx.x;
    const int n  = bx & 7;
    const int wb = (bx >> 3) & 3;
    const int cb = bx >> 5;
    const int w0 = wb * 32;
    {
        const size_t nbase = (size_t)n * C_ * (H_ * W_) + (size_t)h_prev * W_;
        for (int idx = t; idx < C_ * 40; idx += 256) {
            int ci = idx / 40;
            int j  = idx - ci * 40;
            int w  = w0 - PAD_ + j;
            float v = 0.0f;
            if ((unsigned)w < (unsigned)W_)
                v = xprev[nbase + (size_t)ci * (H_ * W_) + w];
            Xs[ci][j] = v;
        }
    }
    __syncthreads();
    const int co = cb * 32 + (t >> 3);
    const int w4 = (t & 7) * 4;
    const float* wr = wsrc + (size_t)co * (C_ * K_);
    float acc0 = 0.f, acc1 = 0.f, acc2 = 0.f, acc3 = 0.f;
    for (int ci = 0; ci < C_; ci++) {
        float wk[K_];
        #pragma unroll
        for (int k = 0; k < K_; k++) wk[k] = wr[ci * K_ + k];
        float xv[12];
        float4 a = *(const float4*)&Xs[ci][w4];
        float4 b = *(const float4*)&Xs[ci][w4 + 4];
        float4 c = *(const float4*)&Xs[ci][w4 + 8];
        xv[0]=a.x; xv[1]=a.y; xv[2]=a.z; xv[3]=a.w;
        xv[4]=b.x; xv[5]=b.y; xv[6]=b.z; xv[7]=b.w;
        xv[8]=c.x; xv[9]=c.y; xv[10]=c.z; xv[11]=c.w;
        #pragma unroll
        for (int k = 0; k < K_; k++) {
            acc0 = fmaf(wk[k], xv[k],     acc0);
            acc1 = fmaf(wk[k], xv[k + 1], acc1);
            acc2 = fmaf(wk[k], xv[k + 2], acc2);
            acc3 = fmaf(wk[k], xv[k + 3], acc3);
        }
    }
    const float b = bias[co];
    const size_t obase = (((size_t)n * C_ + co) * H_ + h_out) * W_ + w0 + w4;
    float4 r = *(const float4*)&radd[obase];
    float4 o;
    o.x = fmaxf(acc0 + b, 0.f) + r.x;
    o.y = fmaxf(acc1 + b, 0.f) + r.y;
    o.z = fmaxf(acc2 + b, 0.f) + r.z;
    o.w = fmaxf(acc3 + b, 0.f) + r.w;
    *(float4*)&yout[obase] = o;
}

extern "C" void kernel_launch(void* const* d_in, const int* in_sizes, int n_in,
                              void* d_out, int out_size, void* d_ws, size_t ws_size,
                              hipStream_t stream) {
    const float* fea    = (const float*)d_in[0];
    const float* weight = (const float*)d_in[1];
    const float* bias   = (const float*)d_in[2];
    float* out = (float*)d_out;

    // ws layout: Wh | Wl | Xt[buf0]h | Xt[buf0]l | Xt[buf1]h | Xt[buf1]l
    const size_t need = (size_t)2 * WELEMS * 2 + (size_t)4 * XT_SZ * 2;

    copy_row0<<<(N_ * C_ * W_ + 255) / 256, 256, 0, stream>>>(fea, out);

    if (ws_size >= need && d_ws != nullptr) {
        f16* wh  = (f16*)d_ws;
        f16* wl  = wh + WELEMS;
        f16* x0h = wl + WELEMS;
        f16* x0l = x0h + XT_SZ;
        f16* x1h = x0l + XT_SZ;
        f16* x1l = x1h + XT_SZ;
        f16* bh[2] = {x0h, x1h};
        f16* bl[2] = {x0l, x1l};

        prep_w<<<(WELEMS + 255) / 256, 256, 0, stream>>>(weight, wh, wl);
        prep_x0<<<(XT_SZ + 255) / 256, 256, 0, stream>>>(fea, x0h, x0l, x1h, x1l);

        int cur = 0;
        for (int h = 1; h < H_; h++) {        // forward: radd = fea row h
            step_mfma<<<256, 1024, 0, stream>>>(bh[cur], bl[cur], bh[1 - cur], bl[1 - cur],
                                                wh, wl, bias, fea, out, h);
            cur ^= 1;
        }
        for (int h = H_ - 2; h >= 1; h--) {   // backward: radd = forward full row h (still in out)
            step_mfma<<<256, 1024, 0, stream>>>(bh[cur], bl[cur], bh[1 - cur], bl[1 - cur],
                                                wh, wl, bias, out, out, h);
            cur ^= 1;
        }
    } else {
        for (int h = 1; h < H_; h++)
            step_f32<<<256, 256, 0, stream>>>(out, fea, out, weight, bias, h - 1, h);
        for (int h = H_ - 2; h >= 1; h--)
            step_f32<<<256, 256, 0, stream>>>(out, out, out, weight, bias, h + 1, h);
    }
}